// Round 5
// baseline (393.890 us; speedup 1.0000x reference)
//
#include <hip/hip_runtime.h>

#define N_NODES 50000
#define N_EDGES 800000
#define D 128
#define BN_EPS 1e-5f

#define NBUCK 391        // ceil(N_NODES / 128)
#define BSHIFT 7         // 128 nodes per bucket
#define S1_BLOCKS 256
#define EPB 3125         // edges per histogram/scatter block (256*3125 == 800000)
#define CVT_BLOCKS 6250  // N_NODES*D/4 / 256
#define PACK_BLOCKS 384  // 3*32768 / 256

typedef __attribute__((ext_vector_type(8))) short bf16x8;
typedef __attribute__((ext_vector_type(4))) float f32x4;

// fp32 -> bf16 (RNE)
__device__ inline unsigned short f2bf(float f) {
    unsigned int u = __float_as_uint(f);
    u = (u + 0x7FFF + ((u >> 16) & 1)) >> 16;
    return (unsigned short)u;
}

// ---------------- fused prep: convert_x | edge histogram | pack_w (+stats zero) ----

__global__ void fused_prep(const float* __restrict__ x, unsigned short* __restrict__ x16,
                           const int* __restrict__ dst, int* __restrict__ hist,
                           const float* __restrict__ Ws0, const float* __restrict__ Wn0,
                           const float* __restrict__ Ws1, const float* __restrict__ Wn1,
                           const float* __restrict__ Ws2, const float* __restrict__ Wn2,
                           unsigned short* __restrict__ Wf, float* __restrict__ statsg) {
    __shared__ int lh[NBUCK];
    const int bid = blockIdx.x, t = threadIdx.x;

    if (bid < CVT_BLOCKS) {
        int idx = bid * 256 + t;
        float4 v = ((const float4*)x)[idx];
        ushort4 o;
        o.x = f2bf(v.x); o.y = f2bf(v.y); o.z = f2bf(v.z); o.w = f2bf(v.w);
        ((ushort4*)x16)[idx] = o;
    } else if (bid < CVT_BLOCKS + S1_BLOCKS) {
        int blk = bid - CVT_BLOCKS;
        for (int i = t; i < NBUCK; i += 256) lh[i] = 0;
        __syncthreads();
        int e0 = blk * EPB;
        for (int i = 0; i < 13; i++) {
            int k = t + i * 256;
            if (k < EPB) atomicAdd(&lh[dst[e0 + k] >> BSHIFT], 1);
        }
        __syncthreads();
        for (int i = t; i < NBUCK; i += 256) hist[blk * NBUCK + i] = lh[i];
    } else {
        if (bid == CVT_BLOCKS + S1_BLOCKS) {       // zero BN stats (both layers)
            statsg[t] = 0.f; statsg[t + 256] = 0.f;
        }
        // pack weights into MFMA B-fragment order:
        // Wf[layer][kt(8)][nt(8)][lane(64)][j(8)], lane l holds
        // B[kt*32 + 8*(l>>4) + j][nt*16 + (l&15)].
        int idx = (bid - (CVT_BLOCKS + S1_BLOCKS)) * 256 + t;
        if (idx < 3 * 32768) {
            int layer = idx >> 15;
            int rem = idx & 32767;
            int kt = rem >> 12;
            int nt = (rem >> 9) & 7;
            int lane = (rem >> 3) & 63;
            int j = rem & 7;
            int k = kt * 32 + (lane >> 4) * 8 + j;
            int n = nt * 16 + (lane & 15);
            const float* Wsrc;
            if (layer == 0) Wsrc = (k < 128) ? Ws0 : Wn0;
            else if (layer == 1) Wsrc = (k < 128) ? Ws1 : Wn1;
            else Wsrc = (k < 128) ? Ws2 : Wn2;
            Wf[idx] = f2bf(Wsrc[(k & 127) * D + n]);
        }
    }
}

// ---------------- S2a: per-bucket exclusive prefix over blocks ----------------

__global__ void s2a(int* __restrict__ hist, int* __restrict__ bucketTotal) {
    __shared__ int s[S1_BLOCKS];
    int b = blockIdx.x, t = threadIdx.x;
    int v = hist[t * NBUCK + b];
    s[t] = v;
    __syncthreads();
    for (int off = 1; off < S1_BLOCKS; off <<= 1) {
        int x = (t >= off) ? s[t - off] : 0;
        __syncthreads();
        s[t] += x;
        __syncthreads();
    }
    hist[t * NBUCK + b] = s[t] - v;
    if (t == S1_BLOCKS - 1) bucketTotal[b] = s[t];
}

// ---------------- S2b: exclusive scan of bucket totals ----------------

__global__ void s2b(const int* __restrict__ bucketTotal, int* __restrict__ bucketStart) {
    __shared__ int s[512];
    int t = threadIdx.x;
    int v = (t < NBUCK) ? bucketTotal[t] : 0;
    s[t] = v;
    __syncthreads();
    for (int off = 1; off < 512; off <<= 1) {
        int x = (t >= off) ? s[t - off] : 0;
        __syncthreads();
        s[t] += x;
        __syncthreads();
    }
    if (t <= NBUCK) bucketStart[t] = s[t] - v;
}

// ---------------- S3: scatter packed records, bucket-grouped ----------------

__global__ void s3_scatter(const int* __restrict__ src, const int* __restrict__ dst,
                           const int* __restrict__ hist, const int* __restrict__ bucketStart,
                           unsigned int* __restrict__ rec) {
    __shared__ int base[NBUCK];
    int blk = blockIdx.x, t = threadIdx.x;
    for (int i = t; i < NBUCK; i += 256)
        base[i] = bucketStart[i] + hist[blk * NBUCK + i];
    __syncthreads();
    int e0 = blk * EPB;
    for (int i = 0; i < 13; i++) {
        int k = t + i * 256;
        if (k < EPB) {
            int e = e0 + k;
            int d = dst[e];
            int p = atomicAdd(&base[d >> BSHIFT], 1);
            rec[p] = ((unsigned)(d & 127) << 16) | (unsigned)src[e];
        }
    }
}

// ---------------- S4: per-bucket counting sort -> CSR + degrees ----------------

__global__ void s4_build(const unsigned int* __restrict__ rec, const int* __restrict__ bucketStart,
                         unsigned short* __restrict__ csr, int* __restrict__ degi,
                         int* __restrict__ offsets, float* __restrict__ inv_deg) {
    __shared__ int lh[128];
    __shared__ int ls[128];
    __shared__ int lcur[128];
    int b = blockIdx.x, t = threadIdx.x;
    int start = bucketStart[b], end = bucketStart[b + 1];

    if (t < 128) lh[t] = 0;
    __syncthreads();
    for (int e = start + t; e < end; e += 256)
        atomicAdd(&lh[rec[e] >> 16], 1);
    __syncthreads();

    int v = 0;
    if (t < 128) { v = lh[t]; ls[t] = v; }
    __syncthreads();
    for (int off = 1; off < 128; off <<= 1) {
        int x = 0;
        if (t < 128 && t >= off) x = ls[t - off];
        __syncthreads();
        if (t < 128) ls[t] += x;
        __syncthreads();
    }

    int node0 = b << BSHIFT;
    if (t < 128) {
        int excl = ls[t] - v;
        lcur[t] = start + excl;
        int node = node0 + t;
        if (node < N_NODES) {
            degi[node] = v;
            offsets[node] = start + excl;
            inv_deg[node] = 1.0f / (float)max(v, 1);
        }
    }
    __syncthreads();
    for (int e = start + t; e < end; e += 256) {
        unsigned r = rec[e];
        int p = atomicAdd(&lcur[r >> 16], 1);
        csr[p] = (unsigned short)(r & 0xFFFFu);
    }
}

// ---------------- fused SAGE layer: aggregate + MFMA GEMM + BN col-stats ----------
// Block = 64 nodes, 256 threads (4 waves).
// Phase 1: mean-gather the block's 64 rows into LDS (bf16).
// Phase 2: out = [h|mean] @ Wf + b via mfma_f32_16x16x32_bf16
//          (C/D layout m89-verified: col=lane&15, row=(lane>>4)*4+reg).
// Epilogue: store bf16 (layers 0/1) or fp32 (layer 2); fused column sum/sumsq.

__global__ __launch_bounds__(256) void sage_fused(
    const unsigned short* __restrict__ h16, const unsigned short* __restrict__ csr,
    const int* __restrict__ offsets, const int* __restrict__ degi,
    const float* __restrict__ inv_deg,
    const unsigned short* __restrict__ Wf, const float* __restrict__ bias,
    unsigned short* __restrict__ out16, float* __restrict__ outf,
    float* __restrict__ stats) {
    __shared__ unsigned short smean[64][136];   // +8 pad: frag reads 2-way (free)
    __shared__ float sstat[256];
    const int t = threadIdx.x;
    const int row0 = blockIdx.x * 64;
    sstat[t] = 0.f;

    // ---- phase 1: mean aggregation into LDS ----
    {
        const int c = t & 15;
        for (int iter = 0; iter < 4; iter++) {
            int nl = iter * 16 + (t >> 4);
            int node = row0 + nl;
            uint4 o = make_uint4(0u, 0u, 0u, 0u);
            if (node < N_NODES) {
                int beg = offsets[node], n = degi[node];
                float a0 = 0.f, a1 = 0.f, a2 = 0.f, a3 = 0.f,
                      a4 = 0.f, a5 = 0.f, a6 = 0.f, a7 = 0.f;
                for (int i = 0; i < n; i++) {
                    int s = csr[beg + i];
                    uint4 v = *(const uint4*)(h16 + (size_t)s * D + c * 8);
                    a0 += __uint_as_float(v.x << 16); a1 += __uint_as_float(v.x & 0xffff0000u);
                    a2 += __uint_as_float(v.y << 16); a3 += __uint_as_float(v.y & 0xffff0000u);
                    a4 += __uint_as_float(v.z << 16); a5 += __uint_as_float(v.z & 0xffff0000u);
                    a6 += __uint_as_float(v.w << 16); a7 += __uint_as_float(v.w & 0xffff0000u);
                }
                float w = inv_deg[node];
                o.x = ((unsigned)f2bf(a1 * w) << 16) | f2bf(a0 * w);
                o.y = ((unsigned)f2bf(a3 * w) << 16) | f2bf(a2 * w);
                o.z = ((unsigned)f2bf(a5 * w) << 16) | f2bf(a4 * w);
                o.w = ((unsigned)f2bf(a7 * w) << 16) | f2bf(a6 * w);
            }
            *(uint4*)&smean[nl][c * 8] = o;
        }
    }
    __syncthreads();

    // ---- phase 2: MFMA ----
    const int lane = t & 63;
    const int wave = t >> 6;
    const int m = lane & 15;
    const int quad = lane >> 4;
    const int wr = wave * 16;
    int arow = row0 + wr + m;
    if (arow >= N_NODES) arow = N_NODES - 1;

    f32x4 acc[8];
#pragma unroll
    for (int i = 0; i < 8; i++) acc[i] = (f32x4)(0.f);

#pragma unroll
    for (int kt = 0; kt < 4; kt++) {   // self half: K 0..127 from global
        bf16x8 af = *(const bf16x8*)(h16 + (size_t)arow * D + kt * 32 + quad * 8);
#pragma unroll
        for (int nt = 0; nt < 8; nt++) {
            bf16x8 bf = *(const bf16x8*)(Wf + ((kt * 8 + nt) * 64 + lane) * 8);
            acc[nt] = __builtin_amdgcn_mfma_f32_16x16x32_bf16(af, bf, acc[nt], 0, 0, 0);
        }
    }
#pragma unroll
    for (int kt = 4; kt < 8; kt++) {   // mean half: K 128..255 from LDS
        bf16x8 af = *(const bf16x8*)&smean[wr + m][(kt - 4) * 32 + quad * 8];
#pragma unroll
        for (int nt = 0; nt < 8; nt++) {
            bf16x8 bf = *(const bf16x8*)(Wf + ((kt * 8 + nt) * 64 + lane) * 8);
            acc[nt] = __builtin_amdgcn_mfma_f32_16x16x32_bf16(af, bf, acc[nt], 0, 0, 0);
        }
    }

    // ---- epilogue: bias, store, fused BN column stats ----
    const bool do16 = (out16 != nullptr);
#pragma unroll
    for (int nt = 0; nt < 8; nt++) {
        int cidx = nt * 16 + m;
        float bv = bias[cidx];
        float s = 0.f, q = 0.f;
#pragma unroll
        for (int reg = 0; reg < 4; reg++) {
            int r = row0 + wr + quad * 4 + reg;
            float v = acc[nt][reg] + bv;
            if (r < N_NODES) {
                if (do16) out16[(size_t)r * D + cidx] = f2bf(v);
                else      outf[(size_t)r * D + cidx] = v;
                s += v; q += v * v;
            }
        }
        if (stats) {
            s += __shfl_xor(s, 16); s += __shfl_xor(s, 32);
            q += __shfl_xor(q, 16); q += __shfl_xor(q, 32);
            if (quad == 0) {
                atomicAdd(&sstat[cidx], s);
                atomicAdd(&sstat[128 + cidx], q);
            }
        }
    }
    if (stats) {
        __syncthreads();
        atomicAdd(&stats[t], sstat[t]);
    }
}

// ---------------- BN normalize + ReLU, in place on bf16 ----------------

__global__ void bn_relu16(unsigned short* __restrict__ h16, const float* __restrict__ stats,
                          const float* __restrict__ gamma, const float* __restrict__ beta) {
    int idx = blockIdx.x * 256 + threadIdx.x;   // over N*D/8 = 800000 uint4s
    if (idx >= N_NODES * (D / 8)) return;
    int cb = (idx & 15) * 8;
    uint4 v = ((const uint4*)h16)[idx];
    unsigned u[4] = {v.x, v.y, v.z, v.w};
    const float invN = 1.0f / (float)N_NODES;
    unsigned ov[4];
#pragma unroll
    for (int p = 0; p < 4; p++) {
        float lo = __uint_as_float(u[p] << 16);
        float hi = __uint_as_float(u[p] & 0xffff0000u);
        int c0 = cb + 2 * p, c1 = c0 + 1;
        float m0 = stats[c0] * invN, m1 = stats[c1] * invN;
        float sc0 = rsqrtf(stats[128 + c0] * invN - m0 * m0 + BN_EPS) * gamma[c0];
        float sc1 = rsqrtf(stats[128 + c1] * invN - m1 * m1 + BN_EPS) * gamma[c1];
        lo = fmaxf((lo - m0) * sc0 + beta[c0], 0.f);
        hi = fmaxf((hi - m1) * sc1 + beta[c1], 0.f);
        ov[p] = ((unsigned)f2bf(hi) << 16) | f2bf(lo);
    }
    uint4 o; o.x = ov[0]; o.y = ov[1]; o.z = ov[2]; o.w = ov[3];
    ((uint4*)h16)[idx] = o;
}

// ---------------- launch ----------------

extern "C" void kernel_launch(void* const* d_in, const int* in_sizes, int n_in,
                              void* d_out, int out_size, void* d_ws, size_t ws_size,
                              hipStream_t stream) {
    const float* x   = (const float*)d_in[0];
    const int* src   = (const int*)d_in[1];
    const int* dst   = (const int*)d_in[2];
    const float* Ws0 = (const float*)d_in[3];
    const float* Wn0 = (const float*)d_in[4];
    const float* b0  = (const float*)d_in[5];
    const float* Ws1 = (const float*)d_in[6];
    const float* Wn1 = (const float*)d_in[7];
    const float* b1  = (const float*)d_in[8];
    const float* Ws2 = (const float*)d_in[9];
    const float* Wn2 = (const float*)d_in[10];
    const float* b2  = (const float*)d_in[11];
    const float* g0  = (const float*)d_in[12];
    const float* be0 = (const float*)d_in[13];
    const float* g1  = (const float*)d_in[14];
    const float* be1 = (const float*)d_in[15];

    char* base = (char*)d_ws;
    size_t NND = (size_t)N_NODES * D;
    unsigned short* X16 = (unsigned short*)base;               // 12.8 MB
    unsigned short* H16 = (unsigned short*)(base + NND * 2);   // 12.8 MB
    char* p = base + 4 * NND;
    unsigned short* Wf = (unsigned short*)p;  p += 3 * 32768 * 2;                  // 192 KB
    int* hist          = (int*)p;             p += (size_t)S1_BLOCKS * NBUCK * 4;  // 400 KB
    int* bucketTotal   = (int*)p;             p += 1568;
    int* bucketStart   = (int*)p;             p += 1568;
    unsigned int* rec  = (unsigned int*)p;    p += (size_t)N_EDGES * 4;            // 3.2 MB
    unsigned short* csr = (unsigned short*)p; p += (size_t)N_EDGES * 2;            // 1.6 MB
    int* degi    = (int*)p;                   p += N_NODES * 4;
    int* offsets = (int*)p;                   p += N_NODES * 4;
    float* inv_deg = (float*)p;               p += N_NODES * 4;
    float* stats   = (float*)p;               p += 2048;  // [2][sum128|sumsq128]
    float* stats0 = stats, *stats1 = stats + 256;

    // prep: feature convert + edge histogram + weight pack + stats zero
    fused_prep<<<CVT_BLOCKS + S1_BLOCKS + PACK_BLOCKS, 256, 0, stream>>>(
        x, X16, dst, hist, Ws0, Wn0, Ws1, Wn1, Ws2, Wn2, Wf, stats);
    s2a<<<NBUCK, 256, 0, stream>>>(hist, bucketTotal);
    s2b<<<1, 512, 0, stream>>>(bucketTotal, bucketStart);
    s3_scatter<<<S1_BLOCKS, 256, 0, stream>>>(src, dst, hist, bucketStart, rec);
    s4_build<<<NBUCK, 256, 0, stream>>>(rec, bucketStart, csr, degi, offsets, inv_deg);

    const int FB = (N_NODES + 63) / 64;          // 782
    const int BN_B = (N_NODES * (D / 8) + 255) / 256;  // 3125

    // Layer 0: X16 -> H16 (+stats0), BN in place
    sage_fused<<<FB, 256, 0, stream>>>(X16, csr, offsets, degi, inv_deg,
                                       Wf, b0, H16, nullptr, stats0);
    bn_relu16<<<BN_B, 256, 0, stream>>>(H16, stats0, g0, be0);

    // Layer 1: H16 -> X16 (+stats1), BN in place
    sage_fused<<<FB, 256, 0, stream>>>(H16, csr, offsets, degi, inv_deg,
                                       Wf + 32768, b1, X16, nullptr, stats1);
    bn_relu16<<<BN_B, 256, 0, stream>>>(X16, stats1, g1, be1);

    // Layer 2: X16 -> d_out (fp32, no stats)
    sage_fused<<<FB, 256, 0, stream>>>(X16, csr, offsets, degi, inv_deg,
                                       Wf + 65536, b2, nullptr, (float*)d_out, nullptr);
}

// Round 6
// 356.584 us; speedup vs baseline: 1.1046x; 1.1046x over previous
//
#include <hip/hip_runtime.h>

#define N_NODES 50000
#define N_EDGES 800000
#define D 128
#define BN_EPS 1e-5f

#define NBUCK 391        // ceil(N_NODES / 128)
#define BSHIFT 7         // 128 nodes per bucket
#define S1_BLOCKS 256
#define EPB 3125         // edges per histogram/scatter block (256*3125 == 800000)
#define CVT_BLOCKS 6250  // N_NODES*D/4 / 256
#define PACK_BLOCKS 384  // 3*32768 / 256

typedef __attribute__((ext_vector_type(8))) short bf16x8;
typedef __attribute__((ext_vector_type(4))) float f32x4;

// fp32 -> bf16 (RNE)
__device__ inline unsigned short f2bf(float f) {
    unsigned int u = __float_as_uint(f);
    u = (u + 0x7FFF + ((u >> 16) & 1)) >> 16;
    return (unsigned short)u;
}

// ---------------- fused prep: convert_x | edge histogram | pack_w (+stats zero) ----

__global__ void fused_prep(const float* __restrict__ x, unsigned short* __restrict__ x16,
                           const int* __restrict__ dst, int* __restrict__ hist,
                           const float* __restrict__ Ws0, const float* __restrict__ Wn0,
                           const float* __restrict__ Ws1, const float* __restrict__ Wn1,
                           const float* __restrict__ Ws2, const float* __restrict__ Wn2,
                           unsigned short* __restrict__ Wf, float* __restrict__ statsg) {
    __shared__ int lh[NBUCK];
    const int bid = blockIdx.x, t = threadIdx.x;

    if (bid < CVT_BLOCKS) {
        int idx = bid * 256 + t;
        float4 v = ((const float4*)x)[idx];
        ushort4 o;
        o.x = f2bf(v.x); o.y = f2bf(v.y); o.z = f2bf(v.z); o.w = f2bf(v.w);
        ((ushort4*)x16)[idx] = o;
    } else if (bid < CVT_BLOCKS + S1_BLOCKS) {
        int blk = bid - CVT_BLOCKS;
        for (int i = t; i < NBUCK; i += 256) lh[i] = 0;
        __syncthreads();
        int e0 = blk * EPB;
        for (int i = 0; i < 13; i++) {
            int k = t + i * 256;
            if (k < EPB) atomicAdd(&lh[dst[e0 + k] >> BSHIFT], 1);
        }
        __syncthreads();
        for (int i = t; i < NBUCK; i += 256) hist[blk * NBUCK + i] = lh[i];
    } else {
        if (bid == CVT_BLOCKS + S1_BLOCKS) {       // zero BN stats (both layers)
            statsg[t] = 0.f; statsg[t + 256] = 0.f;
        }
        // pack weights into MFMA B-fragment order:
        // Wf[layer][kt(8)][nt(8)][lane(64)][j(8)], lane l holds
        // B[kt*32 + 8*(l>>4) + j][nt*16 + (l&15)].
        int idx = (bid - (CVT_BLOCKS + S1_BLOCKS)) * 256 + t;
        if (idx < 3 * 32768) {
            int layer = idx >> 15;
            int rem = idx & 32767;
            int kt = rem >> 12;
            int nt = (rem >> 9) & 7;
            int lane = (rem >> 3) & 63;
            int j = rem & 7;
            int k = kt * 32 + (lane >> 4) * 8 + j;
            int n = nt * 16 + (lane & 15);
            const float* Wsrc;
            if (layer == 0) Wsrc = (k < 128) ? Ws0 : Wn0;
            else if (layer == 1) Wsrc = (k < 128) ? Ws1 : Wn1;
            else Wsrc = (k < 128) ? Ws2 : Wn2;
            Wf[idx] = f2bf(Wsrc[(k & 127) * D + n]);
        }
    }
}

// ---------------- S2a: per-bucket exclusive prefix over blocks ----------------

__global__ void s2a(int* __restrict__ hist, int* __restrict__ bucketTotal) {
    __shared__ int s[S1_BLOCKS];
    int b = blockIdx.x, t = threadIdx.x;
    int v = hist[t * NBUCK + b];
    s[t] = v;
    __syncthreads();
    for (int off = 1; off < S1_BLOCKS; off <<= 1) {
        int x = (t >= off) ? s[t - off] : 0;
        __syncthreads();
        s[t] += x;
        __syncthreads();
    }
    hist[t * NBUCK + b] = s[t] - v;
    if (t == S1_BLOCKS - 1) bucketTotal[b] = s[t];
}

// ---------------- S2b: exclusive scan of bucket totals ----------------

__global__ void s2b(const int* __restrict__ bucketTotal, int* __restrict__ bucketStart) {
    __shared__ int s[512];
    int t = threadIdx.x;
    int v = (t < NBUCK) ? bucketTotal[t] : 0;
    s[t] = v;
    __syncthreads();
    for (int off = 1; off < 512; off <<= 1) {
        int x = (t >= off) ? s[t - off] : 0;
        __syncthreads();
        s[t] += x;
        __syncthreads();
    }
    if (t <= NBUCK) bucketStart[t] = s[t] - v;
}

// ---------------- S3: scatter packed records, bucket-grouped ----------------

__global__ void s3_scatter(const int* __restrict__ src, const int* __restrict__ dst,
                           const int* __restrict__ hist, const int* __restrict__ bucketStart,
                           unsigned int* __restrict__ rec) {
    __shared__ int base[NBUCK];
    int blk = blockIdx.x, t = threadIdx.x;
    for (int i = t; i < NBUCK; i += 256)
        base[i] = bucketStart[i] + hist[blk * NBUCK + i];
    __syncthreads();
    int e0 = blk * EPB;
    for (int i = 0; i < 13; i++) {
        int k = t + i * 256;
        if (k < EPB) {
            int e = e0 + k;
            int d = dst[e];
            int p = atomicAdd(&base[d >> BSHIFT], 1);
            rec[p] = ((unsigned)(d & 127) << 16) | (unsigned)src[e];
        }
    }
}

// ---------------- S4: per-bucket counting sort -> CSR + degrees ----------------

__global__ void s4_build(const unsigned int* __restrict__ rec, const int* __restrict__ bucketStart,
                         unsigned short* __restrict__ csr, int* __restrict__ degi,
                         int* __restrict__ offsets, float* __restrict__ inv_deg) {
    __shared__ int lh[128];
    __shared__ int ls[128];
    __shared__ int lcur[128];
    int b = blockIdx.x, t = threadIdx.x;
    int start = bucketStart[b], end = bucketStart[b + 1];

    if (t < 128) lh[t] = 0;
    __syncthreads();
    for (int e = start + t; e < end; e += 256)
        atomicAdd(&lh[rec[e] >> 16], 1);
    __syncthreads();

    int v = 0;
    if (t < 128) { v = lh[t]; ls[t] = v; }
    __syncthreads();
    for (int off = 1; off < 128; off <<= 1) {
        int x = 0;
        if (t < 128 && t >= off) x = ls[t - off];
        __syncthreads();
        if (t < 128) ls[t] += x;
        __syncthreads();
    }

    int node0 = b << BSHIFT;
    if (t < 128) {
        int excl = ls[t] - v;
        lcur[t] = start + excl;
        int node = node0 + t;
        if (node < N_NODES) {
            degi[node] = v;
            offsets[node] = start + excl;
            inv_deg[node] = 1.0f / (float)max(v, 1);
        }
    }
    __syncthreads();
    for (int e = start + t; e < end; e += 256) {
        unsigned r = rec[e];
        int p = atomicAdd(&lcur[r >> 16], 1);
        csr[p] = (unsigned short)(r & 0xFFFFu);
    }
}

// ---------------- mean aggregation (bf16 gather, fp32 accumulate) ----------------
// Separate kernel on purpose: gather is latency-bound and needs max wave count
// (round-5 fusion into the GEMM block cut TLP 4x and regressed 375->394 us).
// 16 nodes per 256-thread block; 16 lanes per node, one 16B (8 bf16) load per lane.

__global__ void aggregate16(const unsigned short* __restrict__ h16,
                            const unsigned short* __restrict__ csr, const int* __restrict__ offsets,
                            const int* __restrict__ degi, const float* __restrict__ inv_deg,
                            unsigned short* __restrict__ mean16) {
    int node = blockIdx.x * 16 + (threadIdx.x >> 4);
    if (node >= N_NODES) return;
    int c = threadIdx.x & 15;
    int beg = offsets[node], n = degi[node];
    float a0 = 0.f, a1 = 0.f, a2 = 0.f, a3 = 0.f, a4 = 0.f, a5 = 0.f, a6 = 0.f, a7 = 0.f;
    for (int i = 0; i < n; i++) {
        int s = csr[beg + i];
        uint4 v = *(const uint4*)(h16 + (size_t)s * D + c * 8);
        a0 += __uint_as_float(v.x << 16); a1 += __uint_as_float(v.x & 0xffff0000u);
        a2 += __uint_as_float(v.y << 16); a3 += __uint_as_float(v.y & 0xffff0000u);
        a4 += __uint_as_float(v.z << 16); a5 += __uint_as_float(v.z & 0xffff0000u);
        a6 += __uint_as_float(v.w << 16); a7 += __uint_as_float(v.w & 0xffff0000u);
    }
    float w = inv_deg[node];
    uint4 o;
    o.x = ((unsigned)f2bf(a1 * w) << 16) | f2bf(a0 * w);
    o.y = ((unsigned)f2bf(a3 * w) << 16) | f2bf(a2 * w);
    o.z = ((unsigned)f2bf(a5 * w) << 16) | f2bf(a4 * w);
    o.w = ((unsigned)f2bf(a7 * w) << 16) | f2bf(a6 * w);
    *(uint4*)(mean16 + (size_t)node * D + c * 8) = o;
}

// ---------------- MFMA SAGE GEMM + fused BN col-stats ----------------
// out = [h|mean]_bf16 @ Wf + b. Block = 4 waves x 16 rows. No LDS in main loop.
// Epilogue: bf16 store (layers 0/1) or fp32 (layer 2) + column sum/sumsq
// (shuffle over quads -> LDS -> 256 global atomics/block).
// C/D layout (m89-verified): col = lane&15, row = (lane>>4)*4 + reg.

__global__ __launch_bounds__(256) void sage_gemm(
    const unsigned short* __restrict__ h16, const unsigned short* __restrict__ mean16,
    const unsigned short* __restrict__ Wf, const float* __restrict__ bias,
    unsigned short* __restrict__ out16, float* __restrict__ outf,
    float* __restrict__ stats) {
    __shared__ float sstat[256];
    const int t = threadIdx.x;
    const int lane = t & 63;
    const int wave = t >> 6;
    const int m = lane & 15;
    const int quad = lane >> 4;
    const int wrow0 = blockIdx.x * 64 + wave * 16;

    if (stats) {
        sstat[t] = 0.f;
        __syncthreads();
    }

    int arow = wrow0 + m;
    if (arow >= N_NODES) arow = N_NODES - 1;

    f32x4 acc[8];
#pragma unroll
    for (int i = 0; i < 8; i++) acc[i] = (f32x4)(0.f);

#pragma unroll
    for (int kt = 0; kt < 8; kt++) {
        const unsigned short* Asrc = (kt < 4) ? h16 : mean16;
        int kof = (kt & 3) * 32 + quad * 8;
        bf16x8 af = *(const bf16x8*)(Asrc + (size_t)arow * D + kof);
#pragma unroll
        for (int nt = 0; nt < 8; nt++) {
            bf16x8 bf = *(const bf16x8*)(Wf + ((kt * 8 + nt) * 64 + lane) * 8);
            acc[nt] = __builtin_amdgcn_mfma_f32_16x16x32_bf16(af, bf, acc[nt], 0, 0, 0);
        }
    }

    const bool do16 = (out16 != nullptr);
#pragma unroll
    for (int nt = 0; nt < 8; nt++) {
        int cidx = nt * 16 + m;
        float bv = bias[cidx];
        float s = 0.f, q = 0.f;
#pragma unroll
        for (int reg = 0; reg < 4; reg++) {
            int r = wrow0 + quad * 4 + reg;
            float v = acc[nt][reg] + bv;
            if (r < N_NODES) {
                if (do16) out16[(size_t)r * D + cidx] = f2bf(v);
                else      outf[(size_t)r * D + cidx] = v;
                s += v; q += v * v;
            }
        }
        if (stats) {
            s += __shfl_xor(s, 16); s += __shfl_xor(s, 32);
            q += __shfl_xor(q, 16); q += __shfl_xor(q, 32);
            if (quad == 0) {
                atomicAdd(&sstat[cidx], s);
                atomicAdd(&sstat[128 + cidx], q);
            }
        }
    }
    if (stats) {
        __syncthreads();
        atomicAdd(&stats[t], sstat[t]);
    }
}

// ---------------- BN normalize + ReLU, in place on bf16 ----------------

__global__ void bn_relu16(unsigned short* __restrict__ h16, const float* __restrict__ stats,
                          const float* __restrict__ gamma, const float* __restrict__ beta) {
    int idx = blockIdx.x * 256 + threadIdx.x;   // over N*D/8 = 800000 uint4s
    if (idx >= N_NODES * (D / 8)) return;
    int cb = (idx & 15) * 8;
    uint4 v = ((const uint4*)h16)[idx];
    unsigned u[4] = {v.x, v.y, v.z, v.w};
    const float invN = 1.0f / (float)N_NODES;
    unsigned ov[4];
#pragma unroll
    for (int p = 0; p < 4; p++) {
        float lo = __uint_as_float(u[p] << 16);
        float hi = __uint_as_float(u[p] & 0xffff0000u);
        int c0 = cb + 2 * p, c1 = c0 + 1;
        float m0 = stats[c0] * invN, m1 = stats[c1] * invN;
        float sc0 = rsqrtf(stats[128 + c0] * invN - m0 * m0 + BN_EPS) * gamma[c0];
        float sc1 = rsqrtf(stats[128 + c1] * invN - m1 * m1 + BN_EPS) * gamma[c1];
        lo = fmaxf((lo - m0) * sc0 + beta[c0], 0.f);
        hi = fmaxf((hi - m1) * sc1 + beta[c1], 0.f);
        ov[p] = ((unsigned)f2bf(hi) << 16) | f2bf(lo);
    }
    uint4 o; o.x = ov[0]; o.y = ov[1]; o.z = ov[2]; o.w = ov[3];
    ((uint4*)h16)[idx] = o;
}

// ---------------- launch ----------------

extern "C" void kernel_launch(void* const* d_in, const int* in_sizes, int n_in,
                              void* d_out, int out_size, void* d_ws, size_t ws_size,
                              hipStream_t stream) {
    const float* x   = (const float*)d_in[0];
    const int* src   = (const int*)d_in[1];
    const int* dst   = (const int*)d_in[2];
    const float* Ws0 = (const float*)d_in[3];
    const float* Wn0 = (const float*)d_in[4];
    const float* b0  = (const float*)d_in[5];
    const float* Ws1 = (const float*)d_in[6];
    const float* Wn1 = (const float*)d_in[7];
    const float* b1  = (const float*)d_in[8];
    const float* Ws2 = (const float*)d_in[9];
    const float* Wn2 = (const float*)d_in[10];
    const float* b2  = (const float*)d_in[11];
    const float* g0  = (const float*)d_in[12];
    const float* be0 = (const float*)d_in[13];
    const float* g1  = (const float*)d_in[14];
    const float* be1 = (const float*)d_in[15];

    char* base = (char*)d_ws;
    size_t NND = (size_t)N_NODES * D;
    unsigned short* X16    = (unsigned short*)base;               // 12.8 MB
    unsigned short* H16    = (unsigned short*)(base + NND * 2);   // 12.8 MB
    unsigned short* mean16 = (unsigned short*)(base + 2 * NND * 2); // 12.8 MB
    char* p = base + 6 * NND;
    unsigned short* Wf = (unsigned short*)p;  p += 3 * 32768 * 2;                  // 192 KB
    int* hist          = (int*)p;             p += (size_t)S1_BLOCKS * NBUCK * 4;  // 400 KB
    int* bucketTotal   = (int*)p;             p += 1568;
    int* bucketStart   = (int*)p;             p += 1568;
    unsigned int* rec  = (unsigned int*)p;    p += (size_t)N_EDGES * 4;            // 3.2 MB
    unsigned short* csr = (unsigned short*)p; p += (size_t)N_EDGES * 2;            // 1.6 MB
    int* degi    = (int*)p;                   p += N_NODES * 4;
    int* offsets = (int*)p;                   p += N_NODES * 4;
    float* inv_deg = (float*)p;               p += N_NODES * 4;
    float* stats   = (float*)p;               p += 2048;  // [2][sum128|sumsq128]
    float* stats0 = stats, *stats1 = stats + 256;

    // prep: feature convert + edge histogram + weight pack + stats zero
    fused_prep<<<CVT_BLOCKS + S1_BLOCKS + PACK_BLOCKS, 256, 0, stream>>>(
        x, X16, dst, hist, Ws0, Wn0, Ws1, Wn1, Ws2, Wn2, Wf, stats);
    s2a<<<NBUCK, 256, 0, stream>>>(hist, bucketTotal);
    s2b<<<1, 512, 0, stream>>>(bucketTotal, bucketStart);
    s3_scatter<<<S1_BLOCKS, 256, 0, stream>>>(src, dst, hist, bucketStart, rec);
    s4_build<<<NBUCK, 256, 0, stream>>>(rec, bucketStart, csr, degi, offsets, inv_deg);

    const int AGG_B = (N_NODES + 15) / 16;             // 3125
    const int GEMM_B = (N_NODES + 63) / 64;            // 782
    const int BN_B = (N_NODES * (D / 8) + 255) / 256;  // 3125

    // Layer 0: X16 -> H16 (+stats0), BN in place
    aggregate16<<<AGG_B, 256, 0, stream>>>(X16, csr, offsets, degi, inv_deg, mean16);
    sage_gemm<<<GEMM_B, 256, 0, stream>>>(X16, mean16, Wf, b0, H16, nullptr, stats0);
    bn_relu16<<<BN_B, 256, 0, stream>>>(H16, stats0, g0, be0);

    // Layer 1: H16 -> X16 (+stats1), BN in place
    aggregate16<<<AGG_B, 256, 0, stream>>>(H16, csr, offsets, degi, inv_deg, mean16);
    sage_gemm<<<GEMM_B, 256, 0, stream>>>(H16, mean16, Wf + 32768, b1, X16, nullptr, stats1);
    bn_relu16<<<BN_B, 256, 0, stream>>>(X16, stats1, g1, be1);

    // Layer 2: X16 -> d_out (fp32, no stats)
    aggregate16<<<AGG_B, 256, 0, stream>>>(X16, csr, offsets, degi, inv_deg, mean16);
    sage_gemm<<<GEMM_B, 256, 0, stream>>>(X16, mean16, Wf + 65536, b2, nullptr, (float*)d_out, nullptr);
}